// Round 7
// baseline (197.412 us; speedup 1.0000x reference)
//
#include <hip/hip_runtime.h>
#include <hip/hip_bf16.h>

// Problem constants
#define BB 2
#define TT 4096
#define KK 512
#define HH 8
#define SS 64
#define MM 8192  // BB*TT

typedef __attribute__((ext_vector_type(8))) short bf16x8;  // MFMA A/B fragment (8 bf16)
typedef __attribute__((ext_vector_type(4))) float f32x4;   // MFMA C/D fragment
typedef unsigned int u32;
typedef __attribute__((ext_vector_type(2))) u32 u32x2;
typedef __attribute__((ext_vector_type(4))) u32 u32x4;

// Q,K scale: 512^-0.25 * sqrt(log2(e)) -> QK^T lands pre-multiplied by log2(e).
#define SCL_QK 0.25250488f

// packed fp32x2 -> bf16x2 (one v_cvt_pk_bf16_f32)
static __device__ __forceinline__ u32 cvt2(float lo, float hi) {
    u32 r;
    asm("v_cvt_pk_bf16_f32 %0, %1, %2" : "=v"(r) : "v"(lo), "v"(hi));
    return r;
}

// async global->LDS, 16B per lane; LDS dest = wave-uniform base + lane*16
#define GLOAD16(g, l) __builtin_amdgcn_global_load_lds( \
    (const __attribute__((address_space(1))) void*)(g), \
    (__attribute__((address_space(3))) void*)(l), 16, 0, 0)

// K-row permutation for flash: store K row kv at LDS row rho(kv) so the
// QK^T output registers are already in PV's B-fragment layout.
// kv bits {c1,g1,g0,c0,b1,b0} -> rho bits {c1,c0,g1,g0,b1,b0}
static __device__ __forceinline__ int rho(int v) {
    return (v & 0x23) | ((v & 0x04) << 2) | ((v & 0x18) >> 1);
}

// ---------------------------------------------------------------------------
// cvt_bf16: X (8192x512 f32) -> xb bf16; Wq,Wk (x SCL_QK), Wv, Wu -> wb bf16
__global__ __launch_bounds__(256) void cvt_bf16(
    const float* __restrict__ x,
    const float* __restrict__ Wq, const float* __restrict__ Wk,
    const float* __restrict__ Wv, const float* __restrict__ Wu,
    short* __restrict__ xb, short* __restrict__ wb)
{
    const int NX = MM * KK;          // 4194304
    const int NW = KK * KK;          // 262144
    int idx = blockIdx.x * blockDim.x + threadIdx.x;
    int total = (NX + 4 * NW) >> 3;
    for (int g = idx; g < total; g += gridDim.x * blockDim.x) {
        int e = g << 3;
        const float* src; short* dst; float scl = 1.0f;
        if (e < NX) { src = x + e; dst = xb + e; }
        else {
            int gg = e - NX;
            int wsel = gg >> 18;
            int off = gg & (NW - 1);
            src = (wsel == 0 ? Wq : wsel == 1 ? Wk : wsel == 2 ? Wv : Wu) + off;
            dst = wb + gg;
            if (wsel <= 1) scl = SCL_QK;
        }
        float4 a = *(const float4*)src;
        float4 b = *(const float4*)(src + 4);
        a.x *= scl; a.y *= scl; a.z *= scl; a.w *= scl;
        b.x *= scl; b.y *= scl; b.z *= scl; b.w *= scl;
        u32x4 wv = { cvt2(a.x, a.y), cvt2(a.z, a.w), cvt2(b.x, b.y), cvt2(b.z, b.w) };
        *(u32x4*)dst = wv;
    }
}

// ---------------------------------------------------------------------------
// QKV projection: Y = Xb @ Wz^T (both bf16), 128x128 tile, BK=32, 2-phase
// double-buffered gload_lds with XOR seg-swizzle (2-way banks on frag reads).
// z=0,1 (Q,K): swapped-operand MFMA -> 8B stores (b,h,t,s).
// z=2 (V): natural MFMA -> 8B stores transposed (b,h,s,t).
// grid = (KK/128, MM/128, 3), block = 256
__global__ __launch_bounds__(256) void proj_qkv(
    const short* __restrict__ xb, const short* __restrict__ wb,
    short* __restrict__ q, short* __restrict__ k, short* __restrict__ v)
{
    __shared__ short aS[2][128 * 32];
    __shared__ short bS[2][128 * 32];
    int nt = blockIdx.x, mt = blockIdx.y, z = blockIdx.z;
    const short* W = wb + (size_t)z * KK * KK;
    short* dst = (z == 0) ? q : ((z == 1) ? k : v);
    bool tr = (z != 2);
    int tid = threadIdx.x, wave = tid >> 6, lane = tid & 63;
    int lr = lane & 15, lg = lane >> 4;
    int wr = wave >> 1, wc = wave & 1;
    int sri = lane >> 2, ss0 = lane & 3;   // staging: row-in-gload, seg

    const short* Ag = xb + (size_t)(mt * 128) * KK;
    const short* Bg = W + (size_t)(nt * 128) * KK;

    f32x4 acc[4][4];
#pragma unroll
    for (int m = 0; m < 4; ++m)
#pragma unroll
        for (int n = 0; n < 4; ++n) acc[m][n] = (f32x4){0.f, 0.f, 0.f, 0.f};

    auto STAGE = [&](int buf, int k0) {
#pragma unroll
        for (int g = 0; g < 2; ++g) {
            int R0 = wave * 32 + g * 16;
            int srow = R0 + sri;
            int sseg = ss0 ^ ((srow >> 1) & 3);   // pre-swizzled source
            GLOAD16(Ag + (size_t)srow * KK + k0 + sseg * 8, &aS[buf][R0 * 32]);
            GLOAD16(Bg + (size_t)srow * KK + k0 + sseg * 8, &bS[buf][R0 * 32]);
        }
    };

    STAGE(0, 0);
    int cur = 0;
    for (int kt = 0; kt < 16; ++kt) {
        __syncthreads();                       // drains prev stage (vmcnt 0) + sync
        if (kt < 15) STAGE(cur ^ 1, (kt + 1) * 32);   // overlap with compute
        bf16x8 af[4], bw[4];
#pragma unroll
        for (int m = 0; m < 4; ++m) {
            int row = wr * 64 + m * 16 + lr;
            af[m] = *(const bf16x8*)&aS[cur][row * 32 + (lg ^ ((row >> 1) & 3)) * 8];
        }
#pragma unroll
        for (int n = 0; n < 4; ++n) {
            int row = wc * 64 + n * 16 + lr;
            bw[n] = *(const bf16x8*)&bS[cur][row * 32 + (lg ^ ((row >> 1) & 3)) * 8];
        }
        if (tr) {
#pragma unroll
            for (int m = 0; m < 4; ++m)
#pragma unroll
                for (int n = 0; n < 4; ++n)
                    acc[m][n] = __builtin_amdgcn_mfma_f32_16x16x32_bf16(bw[n], af[m], acc[m][n], 0, 0, 0);
        } else {
#pragma unroll
            for (int m = 0; m < 4; ++m)
#pragma unroll
                for (int n = 0; n < 4; ++n)
                    acc[m][n] = __builtin_amdgcn_mfma_f32_16x16x32_bf16(af[m], bw[n], acc[m][n], 0, 0, 0);
        }
        cur ^= 1;
    }

    if (tr) {
        // acc[m][n] = Y^T[f = nt*128+wc*64+n*16+4lg+r][t = mt*128+wr*64+m*16+lr]
        int h = nt * 2 + wc;
#pragma unroll
        for (int n = 0; n < 4; ++n) {
            int s0 = n * 16 + lg * 4;
#pragma unroll
            for (int m = 0; m < 4; ++m) {
                int tg = mt * 128 + wr * 64 + m * 16 + lr;
                int b = tg >> 12, t = tg & (TT - 1);
                u32x2 pk = { cvt2(acc[m][n][0], acc[m][n][1]), cvt2(acc[m][n][2], acc[m][n][3]) };
                *(u32x2*)&dst[((size_t)(b * HH + h) * TT + t) * SS + s0] = pk;
            }
        }
    } else {
        // acc[m][n] = Y[t = mt*128+wr*64+m*16+4lg+r][f = nt*128+wc*64+n*16+lr]
#pragma unroll
        for (int n = 0; n < 4; ++n) {
            int nn = nt * 128 + wc * 64 + n * 16 + lr;
            int h = nn >> 6, s = nn & 63;
#pragma unroll
            for (int m = 0; m < 4; ++m) {
                int m0 = mt * 128 + wr * 64 + m * 16 + lg * 4;
                int b = m0 >> 12, t0 = m0 & (TT - 1);
                u32x2 pk = { cvt2(acc[m][n][0], acc[m][n][1]), cvt2(acc[m][n][2], acc[m][n][3]) };
                *(u32x2*)&dst[(((size_t)(b * HH + h)) * SS + s) * TT + t0] = pk;
            }
        }
    }
}

// ---------------------------------------------------------------------------
// Output projection: out = A @ Wu^T + bu, swapped-operand, 64x128 tile, BK=32,
// 2-phase double-buffered gload_lds + seg-swizzle. grid = (KK/128, MM/64)
__global__ __launch_bounds__(256) void proj_out(
    const short* __restrict__ a, const short* __restrict__ Wub,
    const float* __restrict__ bu, float* __restrict__ out)
{
    __shared__ short aS[2][64 * 32];
    __shared__ short bS[2][128 * 32];
    int nt = blockIdx.x, mt = blockIdx.y;
    int tid = threadIdx.x, wave = tid >> 6, lane = tid & 63;
    int lr = lane & 15, lg = lane >> 4;
    int wr = wave >> 1, wc = wave & 1;
    int sri = lane >> 2, ss0 = lane & 3;

    const short* Ag = a + (size_t)(mt * 64) * KK;
    const short* Bg = Wub + (size_t)(nt * 128) * KK;

    f32x4 acc[2][4];
#pragma unroll
    for (int m = 0; m < 2; ++m)
#pragma unroll
        for (int n = 0; n < 4; ++n) acc[m][n] = (f32x4){0.f, 0.f, 0.f, 0.f};

    auto STAGE = [&](int buf, int k0) {
        {
            int R0 = wave * 16;
            int srow = R0 + sri;
            int sseg = ss0 ^ ((srow >> 1) & 3);
            GLOAD16(Ag + (size_t)srow * KK + k0 + sseg * 8, &aS[buf][R0 * 32]);
        }
#pragma unroll
        for (int g = 0; g < 2; ++g) {
            int R0 = wave * 32 + g * 16;
            int srow = R0 + sri;
            int sseg = ss0 ^ ((srow >> 1) & 3);
            GLOAD16(Bg + (size_t)srow * KK + k0 + sseg * 8, &bS[buf][R0 * 32]);
        }
    };

    STAGE(0, 0);
    int cur = 0;
    for (int kt = 0; kt < 16; ++kt) {
        __syncthreads();
        if (kt < 15) STAGE(cur ^ 1, (kt + 1) * 32);
        bf16x8 af[2], bw[4];
#pragma unroll
        for (int m = 0; m < 2; ++m) {
            int row = wr * 32 + m * 16 + lr;
            af[m] = *(const bf16x8*)&aS[cur][row * 32 + (lg ^ ((row >> 1) & 3)) * 8];
        }
#pragma unroll
        for (int n = 0; n < 4; ++n) {
            int row = wc * 64 + n * 16 + lr;
            bw[n] = *(const bf16x8*)&bS[cur][row * 32 + (lg ^ ((row >> 1) & 3)) * 8];
        }
#pragma unroll
        for (int m = 0; m < 2; ++m)
#pragma unroll
            for (int n = 0; n < 4; ++n)
                acc[m][n] = __builtin_amdgcn_mfma_f32_16x16x32_bf16(bw[n], af[m], acc[m][n], 0, 0, 0);
        cur ^= 1;
    }

    // acc[m][n] = out^T[f = nt*128+wc*64+n*16+4lg+r][t = mt*64+wr*32+m*16+lr]
#pragma unroll
    for (int n = 0; n < 4; ++n) {
        int f0 = nt * 128 + wc * 64 + n * 16 + lg * 4;
        float4 bias4 = *(const float4*)&bu[f0];
#pragma unroll
        for (int m = 0; m < 2; ++m) {
            int t = mt * 64 + wr * 32 + m * 16 + lr;
            float4 ov = { acc[m][n][0] + bias4.x, acc[m][n][1] + bias4.y,
                          acc[m][n][2] + bias4.z, acc[m][n][3] + bias4.w };
            *(float4*)&out[(size_t)t * KK + f0] = ov;
        }
    }
}

// ---------------------------------------------------------------------------
// Flash attention, causal, swapped-operand, exp2 softmax, zero P-LDS,
// kv-split for load balance:
//  slot0: qt = c (0..31), full kv range, writes normalized bf16.
//  slot1/2: qt = 63-c, kv half [0,mid) / [mid,nkv); writes f32 partial O^T
//           (unnormalized) + (m,l) for the merge kernel.
// grid = 1536: u -> xcd=u&7 (bh pinned to XCD for L2), r=u>>3:
//   bh = 2*xcd + (r&1), c = (r>>1)&31, slot = r>>6.
__global__ __launch_bounds__(256) void flash_attn(
    const short* __restrict__ Q, const short* __restrict__ Kv,
    const short* __restrict__ Vt, short* __restrict__ Oout,
    float* __restrict__ opart, float* __restrict__ mlws)
{
    __shared__ short k_lds[64][72];       // [rho(kv)][s]
    __shared__ short v_lds[64][72];       // [s][kv]

    int u = blockIdx.x;
    int xcd = u & 7, r = u >> 3;
    int bh = 2 * xcd + (r & 1);
    int cc = (r >> 1) & 31;
    int slot = r >> 6;                    // 0,1,2
    int qt, klo, khi;
    if (slot == 0) { qt = cc; klo = 0; khi = cc + 1; }
    else {
        qt = 63 - cc;
        int nkv = qt + 1, mid = (nkv + 1) >> 1;
        klo = (slot == 1) ? 0 : mid;
        khi = (slot == 1) ? mid : nkv;
    }

    int tid = threadIdx.x, wave = tid >> 6, lane = tid & 63;
    int lr = lane & 15, lg = lane >> 4;
    int b = bh >> 3, h = bh & 7;

    const short* Qb = Q + (size_t)bh * TT * SS;
    const short* Kb = Kv + (size_t)bh * TT * SS;
    const short* Vb = Vt + (size_t)bh * SS * TT;   // (s, t)

    int urow = tid >> 3, useg = tid & 7;
    int kdr0 = rho(urow), kdr1 = rho(urow + 32);

    int qrow0 = qt * 64 + wave * 16;

    bf16x8 a_q[2];
#pragma unroll
    for (int kc = 0; kc < 2; ++kc)
        a_q[kc] = *(const bf16x8*)&Qb[(size_t)(qrow0 + lr) * SS + kc * 32 + lg * 8];

    f32x4 o[4];
#pragma unroll
    for (int n = 0; n < 4; ++n) o[n] = (f32x4){0.f, 0.f, 0.f, 0.f};
    float m_run = -INFINITY, l_run = 0.f;

    bf16x8 kr0, kr1, vr0, vr1;
    kr0 = *(const bf16x8*)&Kb[(size_t)(klo * 64 + urow) * SS + useg * 8];
    kr1 = *(const bf16x8*)&Kb[(size_t)(klo * 64 + urow + 32) * SS + useg * 8];
    vr0 = *(const bf16x8*)&Vb[(size_t)urow * TT + klo * 64 + useg * 8];
    vr1 = *(const bf16x8*)&Vb[(size_t)(urow + 32) * TT + klo * 64 + useg * 8];

    for (int kt = klo; kt < khi; ++kt) {
        __syncthreads();
        *(bf16x8*)&k_lds[kdr0][useg * 8]      = kr0;
        *(bf16x8*)&k_lds[kdr1][useg * 8]      = kr1;
        *(bf16x8*)&v_lds[urow][useg * 8]      = vr0;
        *(bf16x8*)&v_lds[urow + 32][useg * 8] = vr1;
        if (kt + 1 < khi) {   // async-stage next tile
            int kn = kt + 1;
            kr0 = *(const bf16x8*)&Kb[(size_t)(kn * 64 + urow) * SS + useg * 8];
            kr1 = *(const bf16x8*)&Kb[(size_t)(kn * 64 + urow + 32) * SS + useg * 8];
            vr0 = *(const bf16x8*)&Vb[(size_t)urow * TT + kn * 64 + useg * 8];
            vr1 = *(const bf16x8*)&Vb[(size_t)(urow + 32) * TT + kn * 64 + useg * 8];
        }
        __syncthreads();

        // S^T: sc[ct][r] = S^T[kv = 32*(ct>>1)+8*lg+4*(ct&1)+r][q = lr]
        f32x4 sc[4];
#pragma unroll
        for (int ct = 0; ct < 4; ++ct) sc[ct] = (f32x4){0.f, 0.f, 0.f, 0.f};
        __builtin_amdgcn_s_setprio(1);
#pragma unroll
        for (int kc = 0; kc < 2; ++kc) {
#pragma unroll
            for (int ct = 0; ct < 4; ++ct) {
                bf16x8 kf = *(const bf16x8*)&k_lds[ct * 16 + lr][kc * 32 + lg * 8];
                sc[ct] = __builtin_amdgcn_mfma_f32_16x16x32_bf16(kf, a_q[kc], sc[ct], 0, 0, 0);
            }
        }
        __builtin_amdgcn_s_setprio(0);
        if (kt == qt) {   // causal mask (only the diagonal tile; slot1 never hits it)
            int qq = qrow0 + lr;
#pragma unroll
            for (int ct = 0; ct < 4; ++ct) {
                int kv0 = kt * 64 + (ct >> 1) * 32 + lg * 8 + (ct & 1) * 4;
#pragma unroll
                for (int rr = 0; rr < 4; ++rr)
                    if (kv0 + rr > qq) sc[ct][rr] = -INFINITY;
            }
        }
        float mx = -INFINITY;
#pragma unroll
        for (int ct = 0; ct < 4; ++ct)
#pragma unroll
            for (int rr = 0; rr < 4; ++rr) mx = fmaxf(mx, sc[ct][rr]);
        mx = fmaxf(mx, __shfl_xor(mx, 16));
        mx = fmaxf(mx, __shfl_xor(mx, 32));
        if (!__all(mx <= m_run + 8.0f)) {   // defer-max
            float mnew = fmaxf(m_run, mx);
            float corr = __builtin_amdgcn_exp2f(m_run - mnew);
            l_run *= corr;
#pragma unroll
            for (int st = 0; st < 4; ++st)
#pragma unroll
                for (int rr = 0; rr < 4; ++rr) o[st][rr] *= corr;
            m_run = mnew;
        }
        float s0 = 0.f;
#pragma unroll
        for (int ct = 0; ct < 4; ++ct)
#pragma unroll
            for (int rr = 0; rr < 4; ++rr) {
                float pf = __builtin_amdgcn_exp2f(sc[ct][rr] - m_run);
                sc[ct][rr] = pf;
                s0 += pf;
            }
        s0 += __shfl_xor(s0, 16);
        s0 += __shfl_xor(s0, 32);
        l_run += s0;

        // PV: B-fragment in-register from sc (kv = 32kc + 8lg + j)
        __builtin_amdgcn_s_setprio(1);
#pragma unroll
        for (int kc = 0; kc < 2; ++kc) {
            u32x4 pw = { cvt2(sc[2 * kc][0], sc[2 * kc][1]),
                         cvt2(sc[2 * kc][2], sc[2 * kc][3]),
                         cvt2(sc[2 * kc + 1][0], sc[2 * kc + 1][1]),
                         cvt2(sc[2 * kc + 1][2], sc[2 * kc + 1][3]) };
            bf16x8 pb = __builtin_bit_cast(bf16x8, pw);
#pragma unroll
            for (int st = 0; st < 4; ++st) {
                bf16x8 vf = *(const bf16x8*)&v_lds[st * 16 + lr][kc * 32 + lg * 8];
                o[st] = __builtin_amdgcn_mfma_f32_16x16x32_bf16(vf, pb, o[st], 0, 0, 0);
            }
        }
        __builtin_amdgcn_s_setprio(0);
    }

    if (slot == 0) {
        // final: O^T[s][q=lr] normalized -> bf16 out (b, t, h*64+s)
        float inv = 1.f / l_run;
        int t = qrow0 + lr;
#pragma unroll
        for (int st = 0; st < 4; ++st) {
            u32x2 ov = { cvt2(o[st][0] * inv, o[st][1] * inv), cvt2(o[st][2] * inv, o[st][3] * inv) };
            *(u32x2*)&Oout[(size_t)(b * TT + t) * KK + h * 64 + st * 16 + lg * 4] = ov;
        }
    } else {
        // partial: unnormalized O^T as [q][s] f32 + (m,l)
        // q-within-tile = wave*16 + lr  (BUGFIX r7: wave*16 was missing)
        int pidx = bh * 32 + (qt - 32);
        float* ob = opart + ((size_t)(pidx * 2 + (slot - 1)) << 12);
#pragma unroll
        for (int st = 0; st < 4; ++st)
            *(f32x4*)&ob[(wave * 16 + lr) * 64 + st * 16 + lg * 4] = o[st];
        if (lg == 0) {
            float* mlp = mlws + (size_t)(pidx * 2 + (slot - 1)) * 128;
            mlp[wave * 16 + lr] = m_run;
            mlp[64 + wave * 16 + lr] = l_run;
        }
    }
}

// ---------------------------------------------------------------------------
// merge_halves: combine the two kv-half partials for qt in [32,64).
// grid = 512 (pidx), block = 64 (one q-row each)
__global__ __launch_bounds__(64) void merge_halves(
    const float* __restrict__ opart, const float* __restrict__ mlws,
    short* __restrict__ Oout)
{
    int p = blockIdx.x;                 // 0..511
    int bh = p >> 5, qt = (p & 31) + 32;
    int qq = threadIdx.x;               // 0..63
    const float* ml0 = mlws + (size_t)(p * 2) * 128;
    const float* ml1 = mlws + (size_t)(p * 2 + 1) * 128;
    float m0 = ml0[qq], l0 = ml0[64 + qq];
    float m1 = ml1[qq], l1 = ml1[64 + qq];
    float m = fmaxf(m0, m1);
    float c0 = __builtin_amdgcn_exp2f(m0 - m);
    float c1 = __builtin_amdgcn_exp2f(m1 - m);
    float inv = 1.f / (l0 * c0 + l1 * c1);
    c0 *= inv; c1 *= inv;
    const float* o0 = opart + (((size_t)(p * 2)) << 12) + qq * 64;
    const float* o1 = opart + (((size_t)(p * 2 + 1)) << 12) + qq * 64;
    int b = bh >> 3, h = bh & 7;
    short* dst = Oout + ((size_t)(b * TT) + qt * 64 + qq) * KK + h * 64;
#pragma unroll
    for (int s4 = 0; s4 < 16; ++s4) {
        float4 a0 = ((const float4*)o0)[s4];
        float4 a1 = ((const float4*)o1)[s4];
        u32x2 pk = { cvt2(a0.x * c0 + a1.x * c1, a0.y * c0 + a1.y * c1),
                     cvt2(a0.z * c0 + a1.z * c1, a0.w * c0 + a1.w * c1) };
        *(u32x2*)&dst[s4 * 4] = pk;
    }
}

extern "C" void kernel_launch(void* const* d_in, const int* in_sizes, int n_in,
                              void* d_out, int out_size, void* d_ws, size_t ws_size,
                              hipStream_t stream) {
    const float* x  = (const float*)d_in[0];
    // d_in[1] = padding_mask (all ones; no-op for this problem)
    const float* Wq = (const float*)d_in[2];
    const float* Wk = (const float*)d_in[3];
    const float* Wv = (const float*)d_in[4];
    const float* Wu = (const float*)d_in[5];
    const float* bu = (const float*)d_in[6];
    float* out = (float*)d_out;

    short* q_ws  = (short*)d_ws;                    // (b,h,t,s) bf16
    short* k_ws  = q_ws + (size_t)MM * KK;          // (b,h,t,s) bf16
    short* v_ws  = k_ws + (size_t)MM * KK;          // (b,h,s,t) bf16 (transposed)
    short* a_ws  = v_ws + (size_t)MM * KK;          // Xb first, then attn-out
    short* wb_ws = a_ws + (size_t)MM * KK;          // 4x (512x512) bf16 weights
    float* ml_ws = (float*)(wb_ws + 4 * (size_t)KK * KK);  // 1024 x 128 f32 m/l
    float* opart = out;                             // d_out doubles as partial scratch
                                                    // (1024 x 4096 f32 = exactly out_size)

    cvt_bf16<<<2560, 256, 0, stream>>>(x, Wq, Wk, Wv, Wu, a_ws, wb_ws);

    dim3 gQKV(KK / 128, MM / 128, 3);
    proj_qkv<<<gQKV, 256, 0, stream>>>(a_ws, wb_ws, q_ws, k_ws, v_ws);

    flash_attn<<<1536, 256, 0, stream>>>(q_ws, k_ws, v_ws, a_ws, opart, ml_ws);

    merge_halves<<<512, 64, 0, stream>>>(opart, ml_ws, a_ws);

    dim3 gO(KK / 128, MM / 64);
    proj_out<<<gO, 256, 0, stream>>>(a_ws, wb_ws + 3 * (size_t)KK * KK, bu, out);
}

// Round 9
// 191.162 us; speedup vs baseline: 1.0327x; 1.0327x over previous
//
#include <hip/hip_runtime.h>
#include <hip/hip_bf16.h>

// Problem constants
#define BB 2
#define TT 4096
#define KK 512
#define HH 8
#define SS 64
#define MM 8192  // BB*TT

typedef __attribute__((ext_vector_type(8))) short bf16x8;   // MFMA A/B fragment (8 bf16)
typedef __attribute__((ext_vector_type(4))) float f32x4;    // 16x16 C/D fragment
typedef __attribute__((ext_vector_type(16))) float f32x16;  // 32x32 C/D fragment
typedef unsigned int u32;
typedef __attribute__((ext_vector_type(2))) u32 u32x2;
typedef __attribute__((ext_vector_type(4))) u32 u32x4;

// Q,K scale: 512^-0.25 * sqrt(log2(e)) -> QK^T lands pre-multiplied by log2(e).
#define SCL_QK 0.25250488f

// packed fp32x2 -> bf16x2 (one v_cvt_pk_bf16_f32)
static __device__ __forceinline__ u32 cvt2(float lo, float hi) {
    u32 r;
    asm("v_cvt_pk_bf16_f32 %0, %1, %2" : "=v"(r) : "v"(lo), "v"(hi));
    return r;
}

// async global->LDS, 16B per lane; LDS dest = wave-uniform base + lane*16
#define GLOAD16(g, l) __builtin_amdgcn_global_load_lds( \
    (const __attribute__((address_space(1))) void*)(g), \
    (__attribute__((address_space(3))) void*)(l), 16, 0, 0)

// K-row permutation for 32x32 flash: swap bits 2<->3 of the kv row index.
// Storing K row kv at LDS row swap23(kv) makes QK^T's S^T accumulator regs
// land exactly in PV's B-fragment layout (chunk c of the kv-contraction =
// regs 8*(c&1)..+7 of tile c>>1, in j order).
static __device__ __forceinline__ int swap23(int v) {
    return (v & ~12) | ((v & 4) << 1) | ((v & 8) >> 1);
}

// ---------------------------------------------------------------------------
// cvt_bf16: X (8192x512 f32) -> xb bf16; Wq,Wk (x SCL_QK), Wv, Wu -> wb bf16
__global__ __launch_bounds__(256) void cvt_bf16(
    const float* __restrict__ x,
    const float* __restrict__ Wq, const float* __restrict__ Wk,
    const float* __restrict__ Wv, const float* __restrict__ Wu,
    short* __restrict__ xb, short* __restrict__ wb)
{
    const int NX = MM * KK;          // 4194304
    const int NW = KK * KK;          // 262144
    int idx = blockIdx.x * blockDim.x + threadIdx.x;
    int total = (NX + 4 * NW) >> 3;
    for (int g = idx; g < total; g += gridDim.x * blockDim.x) {
        int e = g << 3;
        const float* src; short* dst; float scl = 1.0f;
        if (e < NX) { src = x + e; dst = xb + e; }
        else {
            int gg = e - NX;
            int wsel = gg >> 18;
            int off = gg & (NW - 1);
            src = (wsel == 0 ? Wq : wsel == 1 ? Wk : wsel == 2 ? Wv : Wu) + off;
            dst = wb + gg;
            if (wsel <= 1) scl = SCL_QK;
        }
        float4 a = *(const float4*)src;
        float4 b = *(const float4*)(src + 4);
        a.x *= scl; a.y *= scl; a.z *= scl; a.w *= scl;
        b.x *= scl; b.y *= scl; b.z *= scl; b.w *= scl;
        u32x4 wv = { cvt2(a.x, a.y), cvt2(a.z, a.w), cvt2(b.x, b.y), cvt2(b.z, b.w) };
        *(u32x4*)dst = wv;
    }
}

// ---------------------------------------------------------------------------
// QKV projection: Y = Xb @ Wz^T (both bf16), 128x128 tile, BK=64, 2-phase
// double-buffered gload_lds with XOR seg-swizzle on the 16B granule.
// z=0,1 (Q,K): swapped-operand MFMA -> 8B stores (b,h,t,s).
// z=2 (V): natural MFMA -> 8B stores transposed (b,h,s,t).
// grid = (KK/128, MM/128, 3), block = 256
__global__ __launch_bounds__(256) void proj_qkv(
    const short* __restrict__ xb, const short* __restrict__ wb,
    short* __restrict__ q, short* __restrict__ k, short* __restrict__ v)
{
    __shared__ short aS[2][128 * 64];
    __shared__ short bS[2][128 * 64];
    int nt = blockIdx.x, mt = blockIdx.y, z = blockIdx.z;
    const short* W = wb + (size_t)z * KK * KK;
    short* dst = (z == 0) ? q : ((z == 1) ? k : v);
    bool tr = (z != 2);
    int tid = threadIdx.x, wave = tid >> 6, lane = tid & 63;
    int lr = lane & 15, lg = lane >> 4;
    int wr = wave >> 1, wc = wave & 1;
    int sri = lane >> 3, ss0 = lane & 7;   // staging: row-in-gload (0..7), seg (0..7)

    const short* Ag = xb + (size_t)(mt * 128) * KK;
    const short* Bg = W + (size_t)(nt * 128) * KK;

    f32x4 acc[4][4];
#pragma unroll
    for (int m = 0; m < 4; ++m)
#pragma unroll
        for (int n = 0; n < 4; ++n) acc[m][n] = (f32x4){0.f, 0.f, 0.f, 0.f};

    auto STAGE = [&](int buf, int k0) {
#pragma unroll
        for (int g = 0; g < 4; ++g) {
            int R0 = wave * 32 + g * 8;
            int srow = R0 + sri;
            int sseg = ss0 ^ (srow & 7);   // pre-swizzled source (linear LDS dest)
            GLOAD16(Ag + (size_t)srow * KK + k0 + sseg * 8, &aS[buf][R0 * 64]);
            GLOAD16(Bg + (size_t)srow * KK + k0 + sseg * 8, &bS[buf][R0 * 64]);
        }
    };

    STAGE(0, 0);
    int cur = 0;
    for (int kt = 0; kt < 8; ++kt) {
        __syncthreads();                         // drains prev stage + sync
        if (kt < 7) STAGE(cur ^ 1, (kt + 1) * 64);   // overlap with compute
        bf16x8 af[4], bw[4];
#pragma unroll
        for (int kc = 0; kc < 2; ++kc) {
#pragma unroll
            for (int m = 0; m < 4; ++m) {
                int row = wr * 64 + m * 16 + lr;
                af[m] = *(const bf16x8*)&aS[cur][row * 64 + ((4 * kc + lg) ^ (row & 7)) * 8];
            }
#pragma unroll
            for (int n = 0; n < 4; ++n) {
                int row = wc * 64 + n * 16 + lr;
                bw[n] = *(const bf16x8*)&bS[cur][row * 64 + ((4 * kc + lg) ^ (row & 7)) * 8];
            }
            if (tr) {
#pragma unroll
                for (int m = 0; m < 4; ++m)
#pragma unroll
                    for (int n = 0; n < 4; ++n)
                        acc[m][n] = __builtin_amdgcn_mfma_f32_16x16x32_bf16(bw[n], af[m], acc[m][n], 0, 0, 0);
            } else {
#pragma unroll
                for (int m = 0; m < 4; ++m)
#pragma unroll
                    for (int n = 0; n < 4; ++n)
                        acc[m][n] = __builtin_amdgcn_mfma_f32_16x16x32_bf16(af[m], bw[n], acc[m][n], 0, 0, 0);
            }
        }
        cur ^= 1;
    }

    if (tr) {
        // acc[m][n] = Y^T[f = nt*128+wc*64+n*16+4lg+r][t = mt*128+wr*64+m*16+lr]
        int h = nt * 2 + wc;
#pragma unroll
        for (int n = 0; n < 4; ++n) {
            int s0 = n * 16 + lg * 4;
#pragma unroll
            for (int m = 0; m < 4; ++m) {
                int tg = mt * 128 + wr * 64 + m * 16 + lr;
                int b = tg >> 12, t = tg & (TT - 1);
                u32x2 pk = { cvt2(acc[m][n][0], acc[m][n][1]), cvt2(acc[m][n][2], acc[m][n][3]) };
                *(u32x2*)&dst[((size_t)(b * HH + h) * TT + t) * SS + s0] = pk;
            }
        }
    } else {
        // acc[m][n] = Y[t = mt*128+wr*64+m*16+4lg+r][f = nt*128+wc*64+n*16+lr]
#pragma unroll
        for (int n = 0; n < 4; ++n) {
            int nn = nt * 128 + wc * 64 + n * 16 + lr;
            int h = nn >> 6, s = nn & 63;
#pragma unroll
            for (int m = 0; m < 4; ++m) {
                int m0 = mt * 128 + wr * 64 + m * 16 + lg * 4;
                int b = m0 >> 12, t0 = m0 & (TT - 1);
                u32x2 pk = { cvt2(acc[m][n][0], acc[m][n][1]), cvt2(acc[m][n][2], acc[m][n][3]) };
                *(u32x2*)&dst[(((size_t)(b * HH + h)) * SS + s) * TT + t0] = pk;
            }
        }
    }
}

// ---------------------------------------------------------------------------
// Output projection: out = A @ Wu^T + bu, swapped-operand, 64x128 tile, BK=64,
// 2-phase double-buffered gload_lds + seg-swizzle. grid = (KK/128, MM/64)
__global__ __launch_bounds__(256) void proj_out(
    const short* __restrict__ a, const short* __restrict__ Wub,
    const float* __restrict__ bu, float* __restrict__ out)
{
    __shared__ short aS[2][64 * 64];
    __shared__ short bS[2][128 * 64];
    int nt = blockIdx.x, mt = blockIdx.y;
    int tid = threadIdx.x, wave = tid >> 6, lane = tid & 63;
    int lr = lane & 15, lg = lane >> 4;
    int wr = wave >> 1, wc = wave & 1;
    int sri = lane >> 3, ss0 = lane & 7;

    const short* Ag = a + (size_t)(mt * 64) * KK;
    const short* Bg = Wub + (size_t)(nt * 128) * KK;

    f32x4 acc[2][4];
#pragma unroll
    for (int m = 0; m < 2; ++m)
#pragma unroll
        for (int n = 0; n < 4; ++n) acc[m][n] = (f32x4){0.f, 0.f, 0.f, 0.f};

    auto STAGE = [&](int buf, int k0) {
#pragma unroll
        for (int g = 0; g < 2; ++g) {
            int R0 = wave * 16 + g * 8;
            int srow = R0 + sri;
            int sseg = ss0 ^ (srow & 7);
            GLOAD16(Ag + (size_t)srow * KK + k0 + sseg * 8, &aS[buf][R0 * 64]);
        }
#pragma unroll
        for (int g = 0; g < 4; ++g) {
            int R0 = wave * 32 + g * 8;
            int srow = R0 + sri;
            int sseg = ss0 ^ (srow & 7);
            GLOAD16(Bg + (size_t)srow * KK + k0 + sseg * 8, &bS[buf][R0 * 64]);
        }
    };

    STAGE(0, 0);
    int cur = 0;
    for (int kt = 0; kt < 8; ++kt) {
        __syncthreads();
        if (kt < 7) STAGE(cur ^ 1, (kt + 1) * 64);
        bf16x8 af[2], bw[4];
#pragma unroll
        for (int kc = 0; kc < 2; ++kc) {
#pragma unroll
            for (int m = 0; m < 2; ++m) {
                int row = wr * 32 + m * 16 + lr;
                af[m] = *(const bf16x8*)&aS[cur][row * 64 + ((4 * kc + lg) ^ (row & 7)) * 8];
            }
#pragma unroll
            for (int n = 0; n < 4; ++n) {
                int row = wc * 64 + n * 16 + lr;
                bw[n] = *(const bf16x8*)&bS[cur][row * 64 + ((4 * kc + lg) ^ (row & 7)) * 8];
            }
#pragma unroll
            for (int m = 0; m < 2; ++m)
#pragma unroll
                for (int n = 0; n < 4; ++n)
                    acc[m][n] = __builtin_amdgcn_mfma_f32_16x16x32_bf16(bw[n], af[m], acc[m][n], 0, 0, 0);
        }
        cur ^= 1;
    }

    // acc[m][n] = out^T[f = nt*128+wc*64+n*16+4lg+r][t = mt*64+wr*32+m*16+lr]
#pragma unroll
    for (int n = 0; n < 4; ++n) {
        int f0 = nt * 128 + wc * 64 + n * 16 + lg * 4;
        float4 bias4 = *(const float4*)&bu[f0];
#pragma unroll
        for (int m = 0; m < 2; ++m) {
            int t = mt * 64 + wr * 32 + m * 16 + lr;
            float4 ov = { acc[m][n][0] + bias4.x, acc[m][n][1] + bias4.y,
                          acc[m][n][2] + bias4.z, acc[m][n][3] + bias4.w };
            *(float4*)&out[(size_t)t * KK + f0] = ov;
        }
    }
}

// ---------------------------------------------------------------------------
// Flash attention, causal, 32x32x16 MFMA, swapped-operand, exp2 softmax,
// zero-cross-lane P assembly via swap23 K-row permutation.
//  - QBLK=128 (4 waves x 32 q-rows), KVBLK=64 (2 MFMA kv-tiles).
//  - S^T acc (tile T, reg rr, hi=lane>>5): kv_in = (rr&3)+4*((rr>>2)&1)+8*hi
//      +16*(rr>>3)+32*T ; q = qbase + (lane&31).
//  - PV chunk c uses regs 8*(c&1)..+7 of tile c>>1 (consecutive cvt_pk pairs).
//  - O^T acc: s = 32*St + (rr&3) + 8*(rr>>2) + 4*hi.
// grid = 512: xcd = u&7 (bh pinned), r = u>>3: bh = 2*xcd+(r&1),
//   i = (r>>1)&15, qt = (r>>5) ? 16+i : 15-i  -> per-CU iter sum = 66.
__global__ __launch_bounds__(256) void flash_attn(
    const short* __restrict__ Q, const short* __restrict__ Kv,
    const short* __restrict__ Vt, short* __restrict__ Oout)
{
    __shared__ short k_lds[64][72];       // [swap23(kv)][d]
    __shared__ short v_lds[64][72];       // [s][kv]

    int u = blockIdx.x;
    int xcd = u & 7, r = u >> 3;
    int bh = 2 * xcd + (r & 1);
    int qi = (r >> 1) & 15;
    int qt = (r >> 5) ? (16 + qi) : (15 - qi);

    int tid = threadIdx.x, wave = tid >> 6, lane = tid & 63;
    int l32 = lane & 31, hi = lane >> 5;
    int b = bh >> 3, h = bh & 7;

    const short* Qb = Q + (size_t)bh * TT * SS;
    const short* Kb = Kv + (size_t)bh * TT * SS;
    const short* Vb = Vt + (size_t)bh * SS * TT;   // (s, t)

    int urow = tid >> 3, useg = tid & 7;           // staging rows 0..31(+32), 16B segs
    int sr0 = swap23(urow), sr1 = sr0 + 32;        // permuted K LDS rows

    int qbase = qt * 128 + wave * 32;
    int qrow = qbase + l32;

    // Q B-fragments: bq[c][j] = Q[qrow][16c + 8hi + j]
    bf16x8 bq[4];
#pragma unroll
    for (int c = 0; c < 4; ++c)
        bq[c] = *(const bf16x8*)&Qb[(size_t)qrow * SS + c * 16 + hi * 8];

    f32x16 oa[2];
#pragma unroll
    for (int T = 0; T < 2; ++T)
#pragma unroll
        for (int rr = 0; rr < 16; ++rr) oa[T][rr] = 0.f;
    float m_run = -INFINITY, l_run = 0.f;

    int nkv = 2 * qt + 2;
    bf16x8 kr0, kr1, vr0, vr1;
    kr0 = *(const bf16x8*)&Kb[(size_t)urow * SS + useg * 8];
    kr1 = *(const bf16x8*)&Kb[(size_t)(urow + 32) * SS + useg * 8];
    vr0 = *(const bf16x8*)&Vb[(size_t)urow * TT + useg * 8];
    vr1 = *(const bf16x8*)&Vb[(size_t)(urow + 32) * TT + useg * 8];

    for (int kt = 0; kt < nkv; ++kt) {
        __syncthreads();
        *(bf16x8*)&k_lds[sr0][useg * 8]       = kr0;
        *(bf16x8*)&k_lds[sr1][useg * 8]       = kr1;
        *(bf16x8*)&v_lds[urow][useg * 8]      = vr0;
        *(bf16x8*)&v_lds[urow + 32][useg * 8] = vr1;
        if (kt + 1 < nkv) {   // async-stage next tile under this tile's compute
            int kn = kt + 1;
            kr0 = *(const bf16x8*)&Kb[(size_t)(kn * 64 + urow) * SS + useg * 8];
            kr1 = *(const bf16x8*)&Kb[(size_t)(kn * 64 + urow + 32) * SS + useg * 8];
            vr0 = *(const bf16x8*)&Vb[(size_t)urow * TT + kn * 64 + useg * 8];
            vr1 = *(const bf16x8*)&Vb[(size_t)(urow + 32) * TT + kn * 64 + useg * 8];
        }
        __syncthreads();

        // QK^T: S^T tiles (kv 0..31, 32..63) x (q = this wave's 32 rows)
        f32x16 sa[2];
#pragma unroll
        for (int T = 0; T < 2; ++T)
#pragma unroll
            for (int rr = 0; rr < 16; ++rr) sa[T][rr] = 0.f;
        __builtin_amdgcn_s_setprio(1);
#pragma unroll
        for (int c = 0; c < 4; ++c) {
            bf16x8 a0 = *(const bf16x8*)&k_lds[l32][c * 16 + hi * 8];
            bf16x8 a1 = *(const bf16x8*)&k_lds[l32 + 32][c * 16 + hi * 8];
            sa[0] = __builtin_amdgcn_mfma_f32_32x32x16_bf16(a0, bq[c], sa[0], 0, 0, 0);
            sa[1] = __builtin_amdgcn_mfma_f32_32x32x16_bf16(a1, bq[c], sa[1], 0, 0, 0);
        }
        __builtin_amdgcn_s_setprio(0);

        // causal mask on diagonal tiles (kt*64 overlaps this block's q range)
        if (kt >= 2 * qt) {
#pragma unroll
            for (int T = 0; T < 2; ++T)
#pragma unroll
                for (int rr = 0; rr < 16; ++rr) {
                    int kv = kt * 64 + (rr & 3) + 4 * ((rr >> 2) & 1) + 8 * hi
                           + 16 * (rr >> 3) + 32 * T;
                    if (kv > qrow) sa[T][rr] = -INFINITY;
                }
        }

        // online softmax (exp2 domain), state per lane (q = l32)
        float mx = -INFINITY;
#pragma unroll
        for (int T = 0; T < 2; ++T)
#pragma unroll
            for (int rr = 0; rr < 16; ++rr) mx = fmaxf(mx, sa[T][rr]);
        mx = fmaxf(mx, __shfl_xor(mx, 32));
        if (!__all(mx <= m_run + 8.0f)) {   // defer-max
            float mnew = fmaxf(m_run, mx);
            float corr = __builtin_amdgcn_exp2f(m_run - mnew);
            l_run *= corr;
#pragma unroll
            for (int T = 0; T < 2; ++T)
#pragma unroll
                for (int rr = 0; rr < 16; ++rr) oa[T][rr] *= corr;
            m_run = mnew;
        }
        float s0 = 0.f;
#pragma unroll
        for (int T = 0; T < 2; ++T)
#pragma unroll
            for (int rr = 0; rr < 16; ++rr) {
                float pf = __builtin_amdgcn_exp2f(sa[T][rr] - m_run);
                sa[T][rr] = pf;
                s0 += pf;
            }
        s0 += __shfl_xor(s0, 32);
        l_run += s0;

        // PV: O^T tiles (s 0..31, 32..63); B chunk c from sa[c>>1] regs 8*(c&1)..
        __builtin_amdgcn_s_setprio(1);
#pragma unroll
        for (int c = 0; c < 4; ++c) {
            const int T = c >> 1, base = 8 * (c & 1);
            u32x4 pw = { cvt2(sa[T][base + 0], sa[T][base + 1]),
                         cvt2(sa[T][base + 2], sa[T][base + 3]),
                         cvt2(sa[T][base + 4], sa[T][base + 5]),
                         cvt2(sa[T][base + 6], sa[T][base + 7]) };
            bf16x8 pb = __builtin_bit_cast(bf16x8, pw);
            bf16x8 av0 = *(const bf16x8*)&v_lds[l32][c * 16 + hi * 8];
            bf16x8 av1 = *(const bf16x8*)&v_lds[l32 + 32][c * 16 + hi * 8];
            oa[0] = __builtin_amdgcn_mfma_f32_32x32x16_bf16(av0, pb, oa[0], 0, 0, 0);
            oa[1] = __builtin_amdgcn_mfma_f32_32x32x16_bf16(av1, pb, oa[1], 0, 0, 0);
        }
        __builtin_amdgcn_s_setprio(0);
    }

    // epilogue: O^T[s][q=l32] normalized -> bf16 out (b, t, h*64+s)
    float inv = 1.f / l_run;
    short* dp = Oout + (size_t)(b * TT + qrow) * KK + h * 64;
#pragma unroll
    for (int St = 0; St < 2; ++St)
#pragma unroll
        for (int qd = 0; qd < 4; ++qd) {
            int s0i = 32 * St + 8 * qd + 4 * hi;
            u32x2 ov = { cvt2(oa[St][4 * qd + 0] * inv, oa[St][4 * qd + 1] * inv),
                         cvt2(oa[St][4 * qd + 2] * inv, oa[St][4 * qd + 3] * inv) };
            *(u32x2*)&dp[s0i] = ov;
        }
}

extern "C" void kernel_launch(void* const* d_in, const int* in_sizes, int n_in,
                              void* d_out, int out_size, void* d_ws, size_t ws_size,
                              hipStream_t stream) {
    const float* x  = (const float*)d_in[0];
    // d_in[1] = padding_mask (all ones; no-op for this problem)
    const float* Wq = (const float*)d_in[2];
    const float* Wk = (const float*)d_in[3];
    const float* Wv = (const float*)d_in[4];
    const float* Wu = (const float*)d_in[5];
    const float* bu = (const float*)d_in[6];
    float* out = (float*)d_out;

    short* q_ws  = (short*)d_ws;                    // (b,h,t,s) bf16
    short* k_ws  = q_ws + (size_t)MM * KK;          // (b,h,t,s) bf16
    short* v_ws  = k_ws + (size_t)MM * KK;          // (b,h,s,t) bf16 (transposed)
    short* a_ws  = v_ws + (size_t)MM * KK;          // Xb first, then attn-out
    short* wb_ws = a_ws + (size_t)MM * KK;          // 4x (512x512) bf16 weights

    cvt_bf16<<<2560, 256, 0, stream>>>(x, Wq, Wk, Wv, Wu, a_ws, wb_ws);

    dim3 gQKV(KK / 128, MM / 128, 3);
    proj_qkv<<<gQKV, 256, 0, stream>>>(a_ws, wb_ws, q_ws, k_ws, v_ws);

    flash_attn<<<512, 256, 0, stream>>>(q_ws, k_ws, v_ws, a_ws);

    dim3 gO(KK / 128, MM / 64);
    proj_out<<<gO, 256, 0, stream>>>(a_ws, wb_ws + 3 * (size_t)KK * KK, bu, out);
}